// Round 17
// baseline (873.005 us; speedup 1.0000x reference)
//
#include <hip/hip_runtime.h>

#define IN_F 4096
#define OUT_F 11008
#define NGROUPS 32
#define M_TOTAL 8192
#define BM 256
#define BN 256
#define BK 64
#define NKT (IN_F / BK)  // 64 K-tiles = 64 phases

typedef signed char s8;
typedef __attribute__((ext_vector_type(4))) int i32x4;
typedef __attribute__((ext_vector_type(4))) float f32x4;

typedef __attribute__((address_space(1))) const void gvoid_t;
typedef __attribute__((address_space(3))) void lvoid_t;

// ---------------- prepass 1: per-row quantize x -> int8 + sx[row] ----------------
__global__ void quant_x_k(const float* __restrict__ x, s8* __restrict__ xq,
                          float* __restrict__ sx) {
  __shared__ float red[256];
  int row = blockIdx.x, t = threadIdx.x;
  const float* xr = x + (size_t)row * IN_F;
  f32x4 v[4];
  float m = 0.f;
#pragma unroll
  for (int i = 0; i < 4; ++i) {
    v[i] = *(const f32x4*)(xr + t * 16 + i * 4);
#pragma unroll
    for (int j = 0; j < 4; ++j) m = fmaxf(m, fabsf(v[i][j]));
  }
  red[t] = m;
  __syncthreads();
  for (int s = 128; s > 0; s >>= 1) {
    if (t < s) red[t] = fmaxf(red[t], red[t + s]);
    __syncthreads();
  }
  float mx = red[0];
  float scale = (mx > 0.f) ? mx * (1.0f / 127.0f) : 1.0f;
  if (t == 0) sx[row] = scale;
  float inv = 1.0f / scale;
  union { char c[16]; i32x4 w; } u;
#pragma unroll
  for (int i = 0; i < 4; ++i)
#pragma unroll
    for (int j = 0; j < 4; ++j) {
      float q = __builtin_rintf(v[i][j] * inv);
      q = fminf(fmaxf(q, -127.f), 127.f);
      u.c[i * 4 + j] = (char)(int)q;
    }
  *(i32x4*)(xq + (size_t)row * IN_F + t * 16) = u.w;
}

// ---------------- prepass 2: pack W int32 -> int8 ----------------
__global__ void pack_w_k(const int* __restrict__ wq, s8* __restrict__ w8) {
  size_t idx = ((size_t)blockIdx.x * blockDim.x + threadIdx.x) * 16;
  const i32x4* p = (const i32x4*)(wq + idx);
  i32x4 a = __builtin_nontemporal_load(p);
  i32x4 b = __builtin_nontemporal_load(p + 1);
  i32x4 c = __builtin_nontemporal_load(p + 2);
  i32x4 d = __builtin_nontemporal_load(p + 3);
  union { char cc[16]; i32x4 w; } u;
#pragma unroll
  for (int j = 0; j < 4; ++j) {
    u.cc[j] = (char)a[j];
    u.cc[4 + j] = (char)b[j];
    u.cc[8 + j] = (char)c[j];
    u.cc[12 + j] = (char)d[j];
  }
  *(i32x4*)(w8 + idx) = u.w;
}

// ------- 256x256 int8 GEMM, BK=64, 3-slot rotation (r13-proven skeleton) -------
// y[m,n] = sx[m] * sum_g s[n,g] * dot_g  (dot exact int32 via mfma_i32_16x16x64_i8)
// LDS: slots smem[3][32768] (A 16K + B 16K int8, 64 B rows, swizzle c ^= (row&6)<<3
// both sides — byte-geometry identical to the bf16 kernel that measured 0 conflicts);
// s-slice float [32][256] at smem+98304 (col-indexed reads -> conflict-free). 128 KiB.
// Phase t: [4 b32 s'-reads g=t>>1][12 b128 frag reads slot t%3][STAGE(t+2)->(t+2)%3]
// [LGKM(0);SB0;PRIO1][32 mfma + fp32 rescale][PRIO0][VMCNT(4)][BAR].
// Ledger: stage target (t+2)%3 = (t-1)%3 — its readers drained at t-1's LGKM(0),
// before BAR(t-1), stage issues after ✓. VMCNT(4) at end of t retires stage(t+1)
// (8 outstanding -> 4) => tile t+1 resident before phase t+1 reads ✓. Tail: t=62
// VMCNT(0) (stage 63 landed), t=63 clean.

#define BAR() __builtin_amdgcn_s_barrier()
#define SB0() __builtin_amdgcn_sched_barrier(0)
#define PRIO1() __builtin_amdgcn_s_setprio(1)
#define PRIO0() __builtin_amdgcn_s_setprio(0)
#define VMCNT(N) asm volatile("s_waitcnt vmcnt(" #N ")" ::: "memory")
#define LGKM(N) asm volatile("s_waitcnt lgkmcnt(" #N ")" ::: "memory")

#define GLD(G, D) __builtin_amdgcn_global_load_lds((gvoid_t*)(G), (lvoid_t*)(D), 16, 0, 0)

// Stage tile KT -> slot S: A 2 rounds + B 2 rounds (8 KB each), 4 loads/thread
#define STAGE(KT, S)                                                       \
  do {                                                                     \
    const s8* gA_ = pAsrc + (size_t)(KT) * 64;                             \
    const s8* gB_ = pBsrc + (size_t)(KT) * 64;                             \
    char* dA_ = smem + (S) * 32768 + tid * 16;                             \
    char* dB_ = dA_ + 16384;                                               \
    GLD(gA_, dA_);                                                         \
    GLD(gA_ + (size_t)128 * IN_F, dA_ + 8192);                             \
    GLD(gB_, dB_);                                                         \
    GLD(gB_ + (size_t)128 * IN_F, dB_ + 8192);                             \
  } while (0)

__global__ __launch_bounds__(512, 2) void gemm_k(const s8* __restrict__ A8,
                                                 const s8* __restrict__ B8,
                                                 const float* __restrict__ scales,
                                                 const float* __restrict__ sx,
                                                 const float* __restrict__ bias,
                                                 float* __restrict__ C) {
  __shared__ __align__(16) char smem[131072];  // 3 slots + s-slice
  float* s_lds = (float*)(smem + 98304);       // [32 g][256 col]

  const int tid = threadIdx.x;
  const int lane = tid & 63;
  const int wv = tid >> 6;
  const int wm = wv >> 2;  // 2 wave-rows (128 rows)
  const int wn = wv & 3;   // 4 wave-cols (64 cols)

  // Band-rasterized, XCD-aware map (nwg = 1376 = 8*172, bijective)
  const int nwg = gridDim.x;
  const int perx = nwg >> 3;
  const int L = ((int)blockIdx.x & 7) * perx + ((int)blockIdx.x >> 3);
  const int band = L >> 7;
  const int rr_ = L & 127;
  const int bn0 = band << 2;
  const int cols = (43 - bn0) < 4 ? (43 - bn0) : 4;
  const int bm = rr_ / cols;
  const int bn = bn0 + rr_ % cols;
  const int row0 = bm * BM;
  const int col0 = bn * BN;

  // staging source (pre-swizzled; involution c ^= (row&6)<<3; 1 B/elem)
  const int c16 = (tid & 3) * 16;
  const int srow = tid >> 2;  // 0..127; +128 round preserves row&6
  const int scol = c16 ^ ((srow & 6) << 3);
  const s8* pAsrc = A8 + (size_t)(row0 + srow) * IN_F + scol;
  const s8* pBsrc = B8 + (size_t)(col0 + srow) * IN_F + scol;

  // fragment read offsets (swizzled); frag row-block stride 16*64 = 1024 B
  const int r16 = lane & 15;
  const int kg = lane >> 4;
  const int aoff = (wm * 128 + r16) * 64 + ((kg * 16) ^ ((r16 & 6) << 3));
  const int boff = (wn * 64 + r16) * 64 + ((kg * 16) ^ ((r16 & 6) << 3));
  const int scol0 = wn * 64 + r16;  // s' read col base

  f32x4 facc[8][4];
#pragma unroll
  for (int m = 0; m < 8; ++m)
#pragma unroll
    for (int n = 0; n < 4; ++n) facc[m][n] = (f32x4){0.f, 0.f, 0.f, 0.f};

  // one-time: stage s-slice [col0..col0+255][32] -> s_lds transposed [g][col]
#pragma unroll
  for (int i = 0; i < 4; ++i) {
    int f = tid * 16 + i * 4;  // 4 consecutive floats of scales slice
    f32x4 sv = *(const f32x4*)(scales + (size_t)col0 * NGROUPS + f);
#pragma unroll
    for (int j = 0; j < 4; ++j) {
      int col = (f + j) >> 5, g = (f + j) & 31;
      s_lds[g * 256 + col] = sv[j];
    }
  }

  // prologue: stage tiles 0,1 -> slots 0,1; vmcnt(4): tile 0 landed
  STAGE(0, 0);
  STAGE(1, 1);
  VMCNT(4);
  BAR();
  SB0();

  i32x4 a[8], b[4];
  float ss[4];
  for (int t = 0; t < NKT - 2; ++t) {  // t = 0..61
    const int rs = t % 3, ws = (t + 2) % 3;
    const int g = t >> 1;
    const char* Ab = smem + rs * 32768;
    const char* Bb = Ab + 16384;
#pragma unroll
    for (int nf = 0; nf < 4; ++nf) ss[nf] = s_lds[g * 256 + scol0 + nf * 16];
#pragma unroll
    for (int mf = 0; mf < 8; ++mf) a[mf] = *(const i32x4*)(Ab + aoff + mf * 1024);
#pragma unroll
    for (int nf = 0; nf < 4; ++nf) b[nf] = *(const i32x4*)(Bb + boff + nf * 1024);
    STAGE(t + 2, ws);
    LGKM(0); SB0(); PRIO1();
#pragma unroll
    for (int nf = 0; nf < 4; ++nf) {
      float sv = ss[nf];
#pragma unroll
      for (int mf = 0; mf < 8; ++mf) {
        i32x4 d = __builtin_amdgcn_mfma_i32_16x16x64_i8(a[mf], b[nf],
                                                        (i32x4){0, 0, 0, 0}, 0, 0, 0);
#pragma unroll
        for (int r = 0; r < 4; ++r) facc[mf][nf][r] += (float)d[r] * sv;
      }
    }
    PRIO0();
    VMCNT(4);  // retires stage(t+1); leaves stage(t+2) in flight
    BAR(); SB0();
  }
#pragma unroll
  for (int tt = 62; tt < 64; ++tt) {  // tail: no stage; 62 drains vmcnt(0)
    const int rs = tt % 3;
    const int g = tt >> 1;
    const char* Ab = smem + rs * 32768;
    const char* Bb = Ab + 16384;
#pragma unroll
    for (int nf = 0; nf < 4; ++nf) ss[nf] = s_lds[g * 256 + scol0 + nf * 16];
#pragma unroll
    for (int mf = 0; mf < 8; ++mf) a[mf] = *(const i32x4*)(Ab + aoff + mf * 1024);
#pragma unroll
    for (int nf = 0; nf < 4; ++nf) b[nf] = *(const i32x4*)(Bb + boff + nf * 1024);
    LGKM(0); SB0(); PRIO1();
#pragma unroll
    for (int nf = 0; nf < 4; ++nf) {
      float sv = ss[nf];
#pragma unroll
      for (int mf = 0; mf < 8; ++mf) {
        i32x4 d = __builtin_amdgcn_mfma_i32_16x16x64_i8(a[mf], b[nf],
                                                        (i32x4){0, 0, 0, 0}, 0, 0, 0);
#pragma unroll
        for (int r = 0; r < 4; ++r) facc[mf][nf][r] += (float)d[r] * sv;
      }
    }
    PRIO0();
    if (tt == 62) { VMCNT(0); }  // stage(63) landed before phase 63 reads
    BAR(); SB0();
  }

  // epilogue: y = sx[row]*acc -> fp16 round -> + fp16(bias) -> fp32 NT store
  const int kg4 = kg * 4;
#pragma unroll
  for (int mf = 0; mf < 8; ++mf) {
    int rb = row0 + wm * 128 + mf * 16 + kg4;
    f32x4 sxv = *(const f32x4*)(sx + rb);
#pragma unroll
    for (int nf = 0; nf < 4; ++nf) {
      int col = col0 + wn * 64 + nf * 16 + r16;
      _Float16 bh = (_Float16)bias[col];
#pragma unroll
      for (int r = 0; r < 4; ++r) {
        _Float16 v = (_Float16)(facc[mf][nf][r] * sxv[r]) + bh;
        __builtin_nontemporal_store((float)v, &C[(size_t)(rb + r) * OUT_F + col]);
      }
    }
  }
}

// ---------------- emergency fallback (ws too small) ----------------
__global__ void naive_k(const float* __restrict__ x, const int* __restrict__ wq,
                        const float* __restrict__ scales, const float* __restrict__ bias,
                        float* __restrict__ out) {
  long idx = (long)blockIdx.x * blockDim.x + threadIdx.x;
  if (idx >= (long)M_TOTAL * OUT_F) return;
  int m = (int)(idx / OUT_F);
  int n = (int)(idx % OUT_F);
  float acc = 0.f;
  for (int g = 0; g < NGROUPS; ++g) {
    float s = scales[n * NGROUPS + g];
    for (int k = g * 128; k < (g + 1) * 128; ++k) {
      _Float16 xv = (_Float16)x[(size_t)m * IN_F + k];
      _Float16 wv = (_Float16)((float)wq[(size_t)n * IN_F + k] * s);
      acc += (float)xv * (float)wv;
    }
  }
  _Float16 r = (_Float16)acc + (_Float16)bias[n];
  out[idx] = (float)r;
}

extern "C" void kernel_launch(void* const* d_in, const int* in_sizes, int n_in,
                              void* d_out, int out_size, void* d_ws, size_t ws_size,
                              hipStream_t stream) {
  const float* x = (const float*)d_in[0];
  const int* wq = (const int*)d_in[1];  // integer inputs arrive as int32
  const float* scales = (const float*)d_in[2];
  const float* bias = (const float*)d_in[3];
  float* out = (float*)d_out;

  const size_t xq_bytes = (size_t)M_TOTAL * IN_F;        // 33.6 MB
  const size_t w8_bytes = (size_t)OUT_F * IN_F;          // 45.1 MB
  const size_t sx_bytes = (size_t)M_TOTAL * sizeof(float);

  if (ws_size >= xq_bytes + w8_bytes + sx_bytes) {
    s8* xq = (s8*)d_ws;
    s8* w8 = (s8*)((char*)d_ws + xq_bytes);
    float* sx = (float*)((char*)d_ws + xq_bytes + w8_bytes);
    quant_x_k<<<M_TOTAL, 256, 0, stream>>>(x, xq, sx);
    pack_w_k<<<(int)(w8_bytes / 16 / 256), 256, 0, stream>>>(wq, w8);
    gemm_k<<<(M_TOTAL / BM) * (OUT_F / BN), 512, 0, stream>>>(xq, w8, scales, sx,
                                                              bias, out);
  } else {
    long total = (long)M_TOTAL * OUT_F;
    naive_k<<<(int)((total + 255) / 256), 256, 0, stream>>>(x, wq, scales, bias, out);
  }
}